// Round 4
// baseline (365.413 us; speedup 1.0000x reference)
//
#include <hip/hip_runtime.h>

#define HH 128
#define WW 128
#define NPIX 16384
#define NC 32
#define NO 32
#define KS 9
#define TAPS 81
#define DIL 2
#define PAD 8
#define SMAX 27.6310211159f   // s <= SMAX <=> exp(-0.5 s) >= 1e-6; dropped-tap bound ~1.4e-5 << 8.8e-4
#define NW (NO * NC * TAPS)   // 82944
#define NWAVE 256             // 64-pixel waves
#define OG 8                  // output groups
#define OPG 4                 // outputs per thread
#define TG 3                  // tap groups (rows tg, tg+3, tg+6)

// ---------------------------------------------------------------------------
// prep: (i<KS)  guidance kv per (tap,pix) + per-(wave,row) live bitmask
//       (i==KS) weight transpose -> [tap][og][o][c] (wave-uniform s_loads in pac)
//       (i==KS+1) init ht=b1, out=b2 so pac tap-groups are pure atomicAdds.
// All f loads coalesced 256 B/wave ((c,pix) layout kept).
// ---------------------------------------------------------------------------
__global__ __launch_bounds__(256) void prep_k_kernel(
    const float* __restrict__ f,
    const float* __restrict__ W1, const float* __restrict__ W2,
    const float* __restrict__ b1, const float* __restrict__ b2,
    float* __restrict__ kbuf, unsigned* __restrict__ live9,
    float* __restrict__ W1t, float* __restrict__ W2t,
    float* __restrict__ ht, float* __restrict__ outb)
{
    const int i = blockIdx.y;
    if (i == KS) {                       // weight transpose (16384 threads)
        for (int t = blockIdx.x * 256 + threadIdx.x; t < NW; t += 64 * 256) {
            int o = t / (NC * TAPS);
            int r = t - o * (NC * TAPS);
            int c = r / TAPS;
            int tap = r - c * TAPS;
            int d = ((tap * OG + (o >> 2)) * OPG + (o & 3)) * NC + c;
            W1t[d] = W1[t];
            W2t[d] = W2[t];
        }
        return;
    }
    if (i == KS + 1) {                   // bias init of both layer outputs
        int pix = blockIdx.x * 256 + threadIdx.x;
#pragma unroll
        for (int o = 0; o < NO; ++o) {
            ht[o * NPIX + pix] = b1[o];
            outb[o * NPIX + pix] = b2[o];
        }
        return;
    }
    const int pix = blockIdx.x * 256 + threadIdx.x;
    const int h = pix >> 7, w = pix & (WW - 1);
    const int wv = pix >> 6;

    float fc[NC];
#pragma unroll
    for (int c = 0; c < NC; ++c) fc[c] = f[c * NPIX + pix];

    const int qh = h + i * DIL - PAD;
    const bool vh = (unsigned)qh < HH;
    unsigned wmask = 0;
#pragma unroll
    for (int j = 0; j < KS; ++j) {
        int qw = w + j * DIL - PAD;
        bool valid = vh & ((unsigned)qw < WW);
        int q = valid ? (qh * WW + qw) : pix;   // safe addr for masked lanes
        float s0 = 0.f, s1 = 0.f, s2 = 0.f, s3 = 0.f;
#pragma unroll
        for (int c4 = 0; c4 < 8; ++c4) {
            float d0 = f[(4 * c4 + 0) * NPIX + q] - fc[4 * c4 + 0];
            float d1 = f[(4 * c4 + 1) * NPIX + q] - fc[4 * c4 + 1];
            float d2 = f[(4 * c4 + 2) * NPIX + q] - fc[4 * c4 + 2];
            float d3 = f[(4 * c4 + 3) * NPIX + q] - fc[4 * c4 + 3];
            s0 = fmaf(d0, d0, s0); s1 = fmaf(d1, d1, s1);
            s2 = fmaf(d2, d2, s2); s3 = fmaf(d3, d3, s3);
        }
        float s = (s0 + s1) + (s2 + s3);
        s = valid ? s : 1e30f;                  // invalid lanes -> kv = 0
        unsigned long long bal = __ballot(s <= SMAX);
        if (bal) {                               // wave-uniform branch
            wmask |= 1u << j;
            kbuf[(i * KS + j) * NPIX + pix] = __expf(-0.5f * s);
        }
    }
    if ((threadIdx.x & 63) == 0) live9[wv * KS + i] = wmask;
}

// ---------------------------------------------------------------------------
// pac: one layer, tap-parallel. Block (px, og, tg) handles kernel rows
// {tg, tg+3, tg+6}; accumulates over its live taps and atomicAdds 4 outputs
// (dest pre-initialized with bias). 6 blocks/CU -> 6 waves/SIMD for latency
// hiding. Ping-pong (xA/xB) software pipeline; weights via s_load; no LDS.
// ---------------------------------------------------------------------------
__global__ __launch_bounds__(256, 6) void pac_kernel(
    const float* __restrict__ in, const float* __restrict__ kbuf,
    const unsigned* __restrict__ live9, const float* __restrict__ Wt,
    float* __restrict__ out)
{
    const int pix = blockIdx.x * 256 + threadIdx.x;
    const int og = blockIdx.y;
    const int tg = blockIdx.z;
    const int h = pix >> 7, w = pix & (WW - 1);
    const int wv = pix >> 6;

    int idx = 0;
    unsigned m = (unsigned)__builtin_amdgcn_readfirstlane((int)live9[wv * KS + tg]);
    auto next = [&]() -> int {                 // wave-uniform live-tap iterator
        while (m == 0) {
            if (++idx >= 3) return -1;
            m = (unsigned)__builtin_amdgcn_readfirstlane(
                    (int)live9[wv * KS + tg + 3 * idx]);
        }
        int j = __builtin_ctz(m);
        m &= m - 1;
        return ((tg + 3 * idx) << 4) | j;
    };

    float acc0 = 0.f, acc1 = 0.f, acc2 = 0.f, acc3 = 0.f;
    float xA[NC], xB[NC];
    float kvA, kvB;
    const float* wpA; const float* wpB;

#define LOAD(tp, X, KV, WP) do {                                           \
        int ii = (tp) >> 4, jj = (tp) & 15;                                \
        int qh_ = h + ii * DIL - PAD;                                      \
        int qw_ = w + jj * DIL - PAD;                                      \
        bool valid_ = ((unsigned)qh_ < HH) & ((unsigned)qw_ < WW);         \
        int q_ = valid_ ? (qh_ * WW + qw_) : pix;                          \
        KV = kbuf[(ii * KS + jj) * NPIX + pix];                            \
        WP = Wt + ((ii * KS + jj) * OG + og) * (OPG * NC);                 \
        _Pragma("unroll")                                                  \
        for (int c = 0; c < NC; ++c) X[c] = in[c * NPIX + q_];             \
    } while (0)

#define CONSUME(X, KV, WP) do {                                            \
        float t0 = 0.f, t1 = 0.f, t2 = 0.f, t3 = 0.f;                      \
        _Pragma("unroll")                                                  \
        for (int c = 0; c < NC; ++c) {                                     \
            float xv = X[c];                                               \
            t0 = fmaf(xv, WP[0 * NC + c], t0);                             \
            t1 = fmaf(xv, WP[1 * NC + c], t1);                             \
            t2 = fmaf(xv, WP[2 * NC + c], t2);                             \
            t3 = fmaf(xv, WP[3 * NC + c], t3);                             \
        }                                                                  \
        acc0 = fmaf(KV, t0, acc0); acc1 = fmaf(KV, t1, acc1);              \
        acc2 = fmaf(KV, t2, acc2); acc3 = fmaf(KV, t3, acc3);              \
    } while (0)

    int tapA = next();
    if (tapA < 0) return;                       // no live taps in this group
    LOAD(tapA, xA, kvA, wpA);
    for (;;) {
        int tapB = next();
        if (tapB < 0) { CONSUME(xA, kvA, wpA); break; }
        LOAD(tapB, xB, kvB, wpB);
        CONSUME(xA, kvA, wpA);
        tapA = next();
        if (tapA < 0) { CONSUME(xB, kvB, wpB); break; }
        LOAD(tapA, xA, kvA, wpA);
        CONSUME(xB, kvB, wpB);
    }
#undef LOAD
#undef CONSUME

    atomicAdd(&out[(og * OPG + 0) * NPIX + pix], acc0);
    atomicAdd(&out[(og * OPG + 1) * NPIX + pix], acc1);
    atomicAdd(&out[(og * OPG + 2) * NPIX + pix], acc2);
    atomicAdd(&out[(og * OPG + 3) * NPIX + pix], acc3);
}

// ---------------------------------------------------------------------------
// Fallback (round-1 proven path, 2 MB ws) in case ws is small.
// ---------------------------------------------------------------------------
#define CHUNK 27
#define NCHUNK 3
#define KMIN 1e-6f
__global__ __launch_bounds__(256) void pac_layer_fuse(
    const float* __restrict__ in, const float* __restrict__ f,
    const float* __restrict__ Wt, const float* __restrict__ bias,
    float* __restrict__ out)
{
    __shared__ float wl[NC * CHUNK * 8];
    const int og = blockIdx.y;
    const int pix = blockIdx.x * 256 + threadIdx.x;
    const int h = pix >> 7, w = pix & (WW - 1);
    float acc[8];
#pragma unroll
    for (int i = 0; i < 8; ++i) acc[i] = 0.f;
    float fc[NC];
#pragma unroll
    for (int c = 0; c < NC; ++c) fc[c] = f[c * NPIX + pix];
    for (int ch = 0; ch < NCHUNK; ++ch) {
        __syncthreads();
        for (int idx = threadIdx.x; idx < NC * CHUNK * 8; idx += 256) {
            int t = idx % CHUNK;
            int c = (idx / CHUNK) % NC;
            int o = idx / (CHUNK * NC);
            wl[(c * CHUNK + t) * 8 + o] =
                Wt[(og * 8 + o) * (NC * TAPS) + c * TAPS + ch * CHUNK + t];
        }
        __syncthreads();
        for (int t = 0; t < CHUNK; ++t) {
            int tap = ch * CHUNK + t;
            int qh = h + (tap / KS) * DIL - PAD;
            int qw = w + (tap % KS) * DIL - PAD;
            bool valid = ((unsigned)qh < HH) & ((unsigned)qw < WW);
            int q = qh * WW + qw;
            float s = 0.f;
#pragma unroll
            for (int c = 0; c < NC; ++c) {
                float fn = valid ? f[c * NPIX + q] : 0.f;
                float d = fn - fc[c];
                s = fmaf(d, d, s);
            }
            float kv = __expf(-0.5f * s);
            if (__all((kv < KMIN) | (!valid))) continue;
            const float* wpp = &wl[t * 8];
#pragma unroll 8
            for (int c = 0; c < NC; ++c) {
                float v = valid ? in[c * NPIX + q] : 0.f;
                v *= kv;
#pragma unroll
                for (int o = 0; o < 8; ++o)
                    acc[o] = fmaf(v, wpp[c * CHUNK * 8 + o], acc[o]);
            }
        }
    }
#pragma unroll
    for (int o = 0; o < 8; ++o)
        out[(og * 8 + o) * NPIX + pix] = acc[o] + bias[og * 8 + o];
}

// ---------------------------------------------------------------------------
extern "C" void kernel_launch(void* const* d_in, const int* in_sizes, int n_in,
                              void* d_out, int out_size, void* d_ws, size_t ws_size,
                              hipStream_t stream)
{
    (void)in_sizes; (void)n_in; (void)out_size;
    const float* x  = (const float*)d_in[0];
    const float* f  = (const float*)d_in[1];
    const float* W1 = (const float*)d_in[2];
    const float* b1 = (const float*)d_in[3];
    const float* W2 = (const float*)d_in[4];
    const float* b2 = (const float*)d_in[5];
    float* out = (float*)d_out;

    float* ws = (float*)d_ws;
    float* kbuf = ws;                                    // TAPS*NPIX
    unsigned* live9 = (unsigned*)(ws + TAPS * NPIX);     // NWAVE*KS
    float* W1t = ws + TAPS * NPIX + NWAVE * KS;          // NW
    float* W2t = W1t + NW;                               // NW
    float* ht  = W2t + NW;                               // NO*NPIX
    const size_t need =
        (size_t)(TAPS * NPIX + NWAVE * KS + 2 * NW + NO * NPIX) * sizeof(float);

    if (ws_size >= need) {
        prep_k_kernel<<<dim3(64, KS + 2), 256, 0, stream>>>(
            f, W1, W2, b1, b2, kbuf, live9, W1t, W2t, ht, out);
        pac_kernel<<<dim3(64, OG, TG), 256, 0, stream>>>(x,  kbuf, live9, W1t, ht);
        pac_kernel<<<dim3(64, OG, TG), 256, 0, stream>>>(ht, kbuf, live9, W2t, out);
    } else {
        float* hbuf = ws;
        pac_layer_fuse<<<dim3(64, 4), 256, 0, stream>>>(x, f, W1, b1, hbuf);
        pac_layer_fuse<<<dim3(64, 4), 256, 0, stream>>>(hbuf, f, W2, b2, out);
    }
}

// Round 5
// 167.056 us; speedup vs baseline: 2.1874x; 2.1874x over previous
//
#include <hip/hip_runtime.h>

#define HH 128
#define WW 128
#define NPIX 16384
#define NC 32
#define NO 32
#define KS 9
#define TAPS 81
#define DIL 2
#define PAD 8
#define SMAX 27.6310211159f   // s <= SMAX <=> exp(-0.5 s) >= 1e-6; dropped-tap err << 8.8e-4
#define NW (NO * NC * TAPS)   // 82944
#define NWAVE 256
#define OG 4                  // output groups (blockIdx.y)
#define OPG 8                 // outputs per thread
#define TG 3                  // tap-row groups: rows {tg, tg+3, tg+6}

// Span trick: a 64-px wave (lane l, base col w0 in {0,64}) needs, for all 9
// taps j of one kernel row, cols w0-8+l+2j in [w0-8, w0+71]. Two coalesced
// loads cover it: A[l]=row[w0-8+l], B[l]=row[w0+56+l]. Extract for tap j:
// t=l+2j (0..79); xv = t<64 ? shfl(A,t) : shfl(B,t) (bpermute wraps mod 64).
// Clamped OOB cols read garbage that is always multiplied by kv==0.

// ---------------------------------------------------------------------------
// prep: (i<KS) per-(row i) guidance kv + per-(wave,row) 9-bit live mask.
//       (i==KS) weight transpose -> [tap][og][o][c] (wave-uniform s_loads).
// ---------------------------------------------------------------------------
__global__ __launch_bounds__(256) void prep_k_kernel(
    const float* __restrict__ f,
    const float* __restrict__ W1, const float* __restrict__ W2,
    float* __restrict__ kbuf, unsigned* __restrict__ live9,
    float* __restrict__ W1t, float* __restrict__ W2t)
{
    const int i = blockIdx.y;
    if (i == KS) {                        // weight transpose
        for (int t = blockIdx.x * 256 + threadIdx.x; t < NW; t += 64 * 256) {
            int o = t / (NC * TAPS);
            int r = t - o * (NC * TAPS);
            int c = r / TAPS;
            int tap = r - c * TAPS;
            int d = ((tap * OG + (o >> 3)) * OPG + (o & 7)) * NC + c;
            W1t[d] = W1[t];
            W2t[d] = W2[t];
        }
        return;
    }
    const int pix = blockIdx.x * 256 + threadIdx.x;
    const int l = threadIdx.x & 63;
    const int h = pix >> 7;
    const int w0 = pix & 64;
    const int wv = pix >> 6;

    const int qh = h + i * DIL - PAD;
    if ((unsigned)qh >= HH) {             // whole row OOB for this wave
        if (l == 0) live9[wv * KS + i] = 0u;
        return;
    }

    float s[KS];
#pragma unroll
    for (int j = 0; j < KS; ++j) s[j] = 0.f;

    const float* rowp = f + qh * WW;
    int colA = w0 - 8 + l;  colA = colA < 0 ? 0 : colA;
    int colB = w0 + 56 + l; colB = colB > WW - 1 ? WW - 1 : colB;
    for (int half = 0; half < 2; ++half) {
        float fc[16], A[16], B[16];
#pragma unroll
        for (int c = 0; c < 16; ++c) {
            int ch = half * 16 + c;
            fc[c] = f[ch * NPIX + pix];
            A[c] = rowp[ch * NPIX + colA];
            B[c] = rowp[ch * NPIX + colB];
        }
#pragma unroll
        for (int j = 0; j < KS; ++j) {
            int t = l + DIL * j;
            bool lo = t < 64;
            float sj = 0.f;
#pragma unroll
            for (int c = 0; c < 16; ++c) {
                float sA = __shfl(A[c], t);
                float sB = __shfl(B[c], t);   // lane t-64 (bpermute wraps)
                float xv = lo ? sA : sB;
                float d = xv - fc[c];
                sj = fmaf(d, d, sj);
            }
            s[j] += sj;
        }
    }
    unsigned wmask = 0;
#pragma unroll
    for (int j = 0; j < KS; ++j) {
        int qw = w0 + l + DIL * j - PAD;
        bool valid = (unsigned)qw < WW;
        float su = valid ? s[j] : 1e30f;      // invalid -> kv = 0
        if (__ballot(su <= SMAX)) {
            wmask |= 1u << j;
            kbuf[(i * KS + j) * NPIX + pix] = __expf(-0.5f * su);
        }
    }
    if (l == 0) live9[wv * KS + i] = wmask;
}

// ---------------------------------------------------------------------------
// pac: block (px, og, tg) handles kernel rows {tg, tg+3, tg+6}; writes its
// partial sums (no bias, no atomics) to part[tg]. Per live row: 64 coalesced
// span loads, then per live tap pure VALU (shuffle-extract + FMA). Weights
// via wave-uniform s_load. No LDS, no atomics.
// ---------------------------------------------------------------------------
__global__ __launch_bounds__(256, 3) void pac_kernel(
    const float* __restrict__ in, const float* __restrict__ kbuf,
    const unsigned* __restrict__ live9, const float* __restrict__ Wt,
    float* __restrict__ part)
{
    const int pix = blockIdx.x * 256 + threadIdx.x;
    const int og = blockIdx.y, tg = blockIdx.z;
    const int l = threadIdx.x & 63;
    const int h = pix >> 7;
    const int w0 = pix & 64;
    const int wv = pix >> 6;

    float acc[OPG];
#pragma unroll
    for (int o = 0; o < OPG; ++o) acc[o] = 0.f;

    int colA = w0 - 8 + l;  colA = colA < 0 ? 0 : colA;
    int colB = w0 + 56 + l; colB = colB > WW - 1 ? WW - 1 : colB;

    for (int r = 0; r < 3; ++r) {
        const int i = tg + 3 * r;
        unsigned m = (unsigned)__builtin_amdgcn_readfirstlane((int)live9[wv * KS + i]);
        if (!m) continue;                          // wave-uniform skip
        int qh = h + i * DIL - PAD;
        qh = qh < 0 ? 0 : (qh > HH - 1 ? HH - 1 : qh);   // kv==0 guards OOB
        const float* rowp = in + qh * WW;
        for (int half = 0; half < 2; ++half) {
            float A[16], B[16];
#pragma unroll
            for (int c = 0; c < 16; ++c) {
                int ch = half * 16 + c;
                A[c] = rowp[ch * NPIX + colA];
                B[c] = rowp[ch * NPIX + colB];
            }
            unsigned mj = m;
            while (mj) {
                int j = __builtin_ctz(mj); mj &= mj - 1;
                int tap = i * KS + j;
                float kv = kbuf[tap * NPIX + pix];
                const float* wp = Wt + (tap * OG + og) * (OPG * NC) + half * 16;
                int t = l + DIL * j;
                bool lo = t < 64;
                float tacc[OPG];
#pragma unroll
                for (int o = 0; o < OPG; ++o) tacc[o] = 0.f;
#pragma unroll
                for (int c = 0; c < 16; ++c) {
                    float sA = __shfl(A[c], t);
                    float sB = __shfl(B[c], t);
                    float xv = lo ? sA : sB;
#pragma unroll
                    for (int o = 0; o < OPG; ++o)
                        tacc[o] = fmaf(xv, wp[o * NC + c], tacc[o]);
                }
#pragma unroll
                for (int o = 0; o < OPG; ++o)
                    acc[o] = fmaf(kv, tacc[o], acc[o]);
            }
        }
    }
#pragma unroll
    for (int o = 0; o < OPG; ++o)
        part[(tg * NO + og * OPG + o) * NPIX + pix] = acc[o];
}

// ---------------------------------------------------------------------------
// reduce: out[o,p] = bias[o] + sum_tg part[tg][o][p]. Fully coalesced.
// ---------------------------------------------------------------------------
__global__ __launch_bounds__(256) void reduce_kernel(
    const float* __restrict__ part, const float* __restrict__ bias,
    float* __restrict__ out)
{
    int tid = blockIdx.x * 256 + threadIdx.x;      // NO*NPIX
    int o = tid >> 14;
    out[tid] = bias[o] + part[tid] + part[NO * NPIX + tid]
             + part[2 * NO * NPIX + tid];
}

// ---------------------------------------------------------------------------
// Fallback (round-1 proven path, 2 MB ws) in case ws is small.
// ---------------------------------------------------------------------------
#define CHUNK 27
#define NCHUNK 3
#define KMIN 1e-6f
__global__ __launch_bounds__(256) void pac_layer_fuse(
    const float* __restrict__ in, const float* __restrict__ f,
    const float* __restrict__ Wt, const float* __restrict__ bias,
    float* __restrict__ out)
{
    __shared__ float wl[NC * CHUNK * 8];
    const int og = blockIdx.y;
    const int pix = blockIdx.x * 256 + threadIdx.x;
    const int h = pix >> 7, w = pix & (WW - 1);
    float acc[8];
#pragma unroll
    for (int i = 0; i < 8; ++i) acc[i] = 0.f;
    float fc[NC];
#pragma unroll
    for (int c = 0; c < NC; ++c) fc[c] = f[c * NPIX + pix];
    for (int ch = 0; ch < NCHUNK; ++ch) {
        __syncthreads();
        for (int idx = threadIdx.x; idx < NC * CHUNK * 8; idx += 256) {
            int t = idx % CHUNK;
            int c = (idx / CHUNK) % NC;
            int o = idx / (CHUNK * NC);
            wl[(c * CHUNK + t) * 8 + o] =
                Wt[(og * 8 + o) * (NC * TAPS) + c * TAPS + ch * CHUNK + t];
        }
        __syncthreads();
        for (int t = 0; t < CHUNK; ++t) {
            int tap = ch * CHUNK + t;
            int qh = h + (tap / KS) * DIL - PAD;
            int qw = w + (tap % KS) * DIL - PAD;
            bool valid = ((unsigned)qh < HH) & ((unsigned)qw < WW);
            int q = qh * WW + qw;
            float s = 0.f;
#pragma unroll
            for (int c = 0; c < NC; ++c) {
                float fn = valid ? f[c * NPIX + q] : 0.f;
                float d = fn - fc[c];
                s = fmaf(d, d, s);
            }
            float kv = __expf(-0.5f * s);
            if (__all((kv < KMIN) | (!valid))) continue;
            const float* wpp = &wl[t * 8];
#pragma unroll 8
            for (int c = 0; c < NC; ++c) {
                float v = valid ? in[c * NPIX + q] : 0.f;
                v *= kv;
#pragma unroll
                for (int o = 0; o < 8; ++o)
                    acc[o] = fmaf(v, wpp[c * CHUNK * 8 + o], acc[o]);
            }
        }
    }
#pragma unroll
    for (int o = 0; o < 8; ++o)
        out[(og * 8 + o) * NPIX + pix] = acc[o] + bias[og * 8 + o];
}

// ---------------------------------------------------------------------------
extern "C" void kernel_launch(void* const* d_in, const int* in_sizes, int n_in,
                              void* d_out, int out_size, void* d_ws, size_t ws_size,
                              hipStream_t stream)
{
    (void)in_sizes; (void)n_in; (void)out_size;
    const float* x  = (const float*)d_in[0];
    const float* f  = (const float*)d_in[1];
    const float* W1 = (const float*)d_in[2];
    const float* b1 = (const float*)d_in[3];
    const float* W2 = (const float*)d_in[4];
    const float* b2 = (const float*)d_in[5];
    float* out = (float*)d_out;

    float* ws = (float*)d_ws;
    float* kbuf = ws;                                    // TAPS*NPIX
    unsigned* live9 = (unsigned*)(ws + TAPS * NPIX);     // NWAVE*KS
    float* W1t = ws + TAPS * NPIX + NWAVE * KS;          // NW
    float* W2t = W1t + NW;                               // NW
    float* ht  = W2t + NW;                               // NO*NPIX
    float* part = ht + NO * NPIX;                        // 3*NO*NPIX
    const size_t need =
        (size_t)(TAPS * NPIX + NWAVE * KS + 2 * NW + 4 * NO * NPIX) * sizeof(float);

    if (ws_size >= need) {
        prep_k_kernel<<<dim3(64, KS + 1), 256, 0, stream>>>(
            f, W1, W2, kbuf, live9, W1t, W2t);
        pac_kernel<<<dim3(64, OG, TG), 256, 0, stream>>>(x, kbuf, live9, W1t, part);
        reduce_kernel<<<NO * NPIX / 256, 256, 0, stream>>>(part, b1, ht);
        pac_kernel<<<dim3(64, OG, TG), 256, 0, stream>>>(ht, kbuf, live9, W2t, part);
        reduce_kernel<<<NO * NPIX / 256, 256, 0, stream>>>(part, b2, out);
    } else {
        float* hbuf = ws;
        pac_layer_fuse<<<dim3(64, 4), 256, 0, stream>>>(x, f, W1, b1, hbuf);
        pac_layer_fuse<<<dim3(64, 4), 256, 0, stream>>>(hbuf, f, W2, b2, out);
    }
}